// Round 28
// baseline (822.076 us; speedup 1.0000x reference)
//
#include <hip/hip_runtime.h>
#include <hip/hip_bf16.h>
#include <math.h>

typedef __attribute__((ext_vector_type(4))) float f32x4;
typedef __attribute__((ext_vector_type(8))) short short8;
typedef __attribute__((ext_vector_type(4))) unsigned short ushort4v;

__device__ __forceinline__ unsigned short f2bf(float f) {
    return __builtin_bit_cast(unsigned short, __float2bfloat16(f));
}

__device__ __forceinline__ void gload16(const void* g, void* l) {
    __builtin_amdgcn_global_load_lds(
        (const __attribute__((address_space(1))) unsigned int*)g,
        (__attribute__((address_space(3))) unsigned int*)l, 16, 0, 0);
}

#define WAITV6() asm volatile("s_waitcnt vmcnt(6)" ::: "memory")
#define WAITV4() asm volatile("s_waitcnt vmcnt(4)" ::: "memory")
#define WAITV0() asm volatile("s_waitcnt vmcnt(0)" ::: "memory")

// ---------------------------------------------------------------------------
// Transpose-cast: in f32 [K][N] (layer z) -> out bf16 [N][K] (k-contiguous)
// ---------------------------------------------------------------------------
__global__ __launch_bounds__(256)
void tc_kernel(const float* __restrict__ in, __hip_bfloat16* __restrict__ out,
               int N, int K)
{
    __shared__ float tile[64][65];
    const size_t loff = (size_t)blockIdx.z * K * N;
    const int k0 = blockIdx.x * 64, n0 = blockIdx.y * 64;
    const int t = threadIdx.x;
    {
        int kk = t >> 2, nb = (t & 3) * 16;
        const float* src = in + loff + (size_t)(k0 + kk) * N + n0 + nb;
        #pragma unroll
        for (int j = 0; j < 4; ++j) {
            float4 v = *(const float4*)(src + j * 4);
            tile[kk][nb + j*4 + 0] = v.x; tile[kk][nb + j*4 + 1] = v.y;
            tile[kk][nb + j*4 + 2] = v.z; tile[kk][nb + j*4 + 3] = v.w;
        }
    }
    __syncthreads();
    {
        int nn = t >> 2, kb = (t & 3) * 16;
        __hip_bfloat16* dst = out + loff + (size_t)(n0 + nn) * K + k0 + kb;
        short8 w0, w1;
        #pragma unroll
        for (int j = 0; j < 8; ++j) w0[j] = (short)f2bf(tile[kb + j][nn]);
        #pragma unroll
        for (int j = 0; j < 8; ++j) w1[j] = (short)f2bf(tile[kb + 8 + j][nn]);
        *(short8*)dst = w0;
        *(short8*)(dst + 8) = w1;
    }
}

// ---------------------------------------------------------------------------
// Embedding (f32 out)
// ---------------------------------------------------------------------------
__global__ __launch_bounds__(256)
void embed_kernel(const int* __restrict__ ids, const float* __restrict__ wte,
                  const float* __restrict__ wpe, float* __restrict__ h)
{
    int row  = blockIdx.x;
    int tpos = row & 1023;
    int id   = ids[row];
    float4 a = ((const float4*)(wte + (size_t)id * 1024))[threadIdx.x];
    float4 p = ((const float4*)(wpe + (size_t)tpos * 1024))[threadIdx.x];
    float4 o; o.x = a.x + p.x; o.y = a.y + p.y; o.z = a.z + p.z; o.w = a.w + p.w;
    ((float4*)(h + (size_t)row * 1024))[threadIdx.x] = o;
}

// ---------------------------------------------------------------------------
// LayerNorm: f32 in, BF16 out
// ---------------------------------------------------------------------------
__global__ __launch_bounds__(256)
void ln_kernel(const float* __restrict__ x, const float* __restrict__ g,
               const float* __restrict__ b, __hip_bfloat16* __restrict__ out)
{
    size_t row = blockIdx.x;
    float4 v = ((const float4*)(x + row * 1024))[threadIdx.x];
    float s  = v.x + v.y + v.z + v.w;
    float s2 = v.x*v.x + v.y*v.y + v.z*v.z + v.w*v.w;
    #pragma unroll
    for (int off = 32; off; off >>= 1) {
        s  += __shfl_xor(s, off);
        s2 += __shfl_xor(s2, off);
    }
    __shared__ float rs[4], rs2[4];
    int wave = threadIdx.x >> 6;
    if ((threadIdx.x & 63) == 0) { rs[wave] = s; rs2[wave] = s2; }
    __syncthreads();
    s  = rs[0] + rs[1] + rs[2] + rs[3];
    s2 = rs2[0] + rs2[1] + rs2[2] + rs2[3];
    float mean = s * (1.f / 1024.f);
    float var  = s2 * (1.f / 1024.f) - mean * mean;
    float rstd = rsqrtf(var + 1e-5f);
    float4 gg = ((const float4*)g)[threadIdx.x];
    float4 bb = ((const float4*)b)[threadIdx.x];
    ushort4v ov;
    ov[0] = f2bf((v.x - mean) * rstd * gg.x + bb.x);
    ov[1] = f2bf((v.y - mean) * rstd * gg.y + bb.y);
    ov[2] = f2bf((v.z - mean) * rstd * gg.z + bb.z);
    ov[3] = f2bf((v.w - mean) * rstd * gg.w + bb.w);
    ((ushort4v*)(out + row * 1024))[threadIdx.x] = ov;
}

// ---------------------------------------------------------------------------
// Layer GEMM (r26/r27, proven): 3-deep counted-vmcnt pipeline, BN=64.
// ---------------------------------------------------------------------------
template<bool OUT_BF16, bool GELU_ACT>
__global__ __launch_bounds__(256)
void gemm_p3(const __hip_bfloat16* __restrict__ A,
             const __hip_bfloat16* __restrict__ Bt,
             const float* __restrict__ bias, const float* __restrict__ resid,
             void* __restrict__ Cout, int M, int N, int K, int GN)
{
    __shared__ unsigned char smem[73728];
    int mblk, pnl;
    {
        int bid = blockIdx.x;
        int x = bid & 7, j = bid >> 3;
        int pw = GN >> 3;
        int whole = pw * 128;
        if (bid < whole) { pnl = x + 8 * (j >> 4); mblk = j & 15; }
        else { int r = bid - whole; pnl = (pw << 3) + (r >> 4); mblk = r & 15; }
    }
    const int m0 = mblk * 128;
    const int n0 = pnl * 64;
    const int t    = threadIdx.x;
    const int lane = t & 63;
    const int wave = t >> 6;
    const int wm = (wave & 1) * 64;
    const int wn = (wave >> 1) * 32;

    f32x4 acc[4][2];
    #pragma unroll
    for (int i = 0; i < 4; ++i)
        #pragma unroll
        for (int j = 0; j < 2; ++j) {
            acc[i][j][0] = 0.f; acc[i][j][1] = 0.f; acc[i][j][2] = 0.f; acc[i][j][3] = 0.f;
        }

    const int l8 = lane >> 3;
    const int lc = (lane & 7) ^ l8;
    const __hip_bfloat16* agp[4];
    const __hip_bfloat16* bgp[2];
    int aoff[4];
    int boff[2];
    #pragma unroll
    for (int i = 0; i < 4; ++i) {
        int row = wave * 32 + i * 8 + l8;
        agp[i]  = A + (size_t)(m0 + row) * K + lc * 8;
        aoff[i] = (wave * 32 + i * 8) * 128;
    }
    #pragma unroll
    for (int i = 0; i < 2; ++i) {
        int row = wave * 16 + i * 8 + l8;
        bgp[i]  = Bt + (size_t)(n0 + row) * K + lc * 8;
        boff[i] = (wave * 16 + i * 8) * 128;
    }

    int a0 = 0,     a1 = 16384, a2 = 32768;
    int b0 = 49152, b1 = 57344, b2 = 65536;

    #pragma unroll
    for (int i = 0; i < 4; ++i) gload16(agp[i], smem + a0 + aoff[i]);
    #pragma unroll
    for (int i = 0; i < 2; ++i) gload16(bgp[i], smem + b0 + boff[i]);
    if (64 < K) {
        #pragma unroll
        for (int i = 0; i < 4; ++i) gload16(agp[i] + 64, smem + a1 + aoff[i]);
        #pragma unroll
        for (int i = 0; i < 2; ++i) gload16(bgp[i] + 64, smem + b1 + boff[i]);
    }

    for (int k0 = 0; k0 < K; k0 += 64) {
        if (k0 + 64 < K) { WAITV6(); } else { WAITV0(); }
        __builtin_amdgcn_s_barrier();
        if (k0 + 128 < K) {
            #pragma unroll
            for (int i = 0; i < 4; ++i) gload16(agp[i] + k0 + 128, smem + a2 + aoff[i]);
            #pragma unroll
            for (int i = 0; i < 2; ++i) gload16(bgp[i] + k0 + 128, smem + b2 + boff[i]);
        }
        const unsigned char* abuf = smem + a0;
        const unsigned char* bbuf = smem + b0;
        const int lr = lane & 15;
        const int lk = lane >> 4;
        #pragma unroll
        for (int ks = 0; ks < 2; ++ks) {
            int chunk = ks * 4 + lk;
            short8 af[4], bfr[2];
            #pragma unroll
            for (int m = 0; m < 4; ++m) {
                int row = wm + m * 16 + lr;
                af[m] = *(const short8*)(abuf + row * 128 + ((chunk * 16) ^ ((row & 7) << 4)));
            }
            #pragma unroll
            for (int n = 0; n < 2; ++n) {
                int nn = wn + n * 16 + lr;
                bfr[n] = *(const short8*)(bbuf + nn * 128 + ((chunk * 16) ^ ((nn & 7) << 4)));
            }
            #pragma unroll
            for (int m = 0; m < 4; ++m)
                #pragma unroll
                for (int n = 0; n < 2; ++n)
                    acc[m][n] = __builtin_amdgcn_mfma_f32_16x16x32_bf16(af[m], bfr[n], acc[m][n], 0, 0, 0);
        }
        int ta = a0; a0 = a1; a1 = a2; a2 = ta;
        int tb = b0; b0 = b1; b1 = b2; b2 = tb;
    }

    const int lr = lane & 15;
    const int lq = lane >> 4;
    float bv[2];
    #pragma unroll
    for (int n = 0; n < 2; ++n)
        bv[n] = bias ? bias[n0 + wn + n * 16 + lr] : 0.f;
    #pragma unroll
    for (int m = 0; m < 4; ++m) {
        int rbase = m0 + wm + m * 16 + lq * 4;
        #pragma unroll
        for (int j = 0; j < 4; ++j) {
            int row = rbase + j;
            #pragma unroll
            for (int n = 0; n < 2; ++n) {
                int col = n0 + wn + n * 16 + lr;
                float v = acc[m][n][j] + bv[n];
                if (resid) v += resid[(size_t)row * N + col];
                if (GELU_ACT) v = 0.5f * v * (1.f + erff(v * 0.70710678118654752f));
                if (OUT_BF16)
                    ((__hip_bfloat16*)Cout)[(size_t)row * N + col] = __float2bfloat16(v);
                else
                    ((float*)Cout)[(size_t)row * N + col] = v;
            }
        }
    }
}

// ---------------------------------------------------------------------------
// LM-head GEMM: counted-vmcnt pipeline at BN=128 with MIXED buffer depths.
// A (L2-resident) 2 buffers, 1-phase lookahead; B (HBM) 3 buffers, 2-phase.
// Per-thread per-tile loads: 4 A + 4 B. Steady-state queue at loop top:
// {B(t), A(t), B(t+1)} = 12 -> vmcnt(4) drains B(t),A(t). Last iter vmcnt(0).
// LDS 80KB -> 2 blocks/CU. Panel swizzle + NT f32 stores (r25-proven).
// ---------------------------------------------------------------------------
__global__ __launch_bounds__(256)
void gemm_lm3(const __hip_bfloat16* __restrict__ A,
              const __hip_bfloat16* __restrict__ Bt,
              float* __restrict__ Cout, int M, int N, int K, int GN)
{
    __shared__ unsigned char smem[81920];
    // A bufs @0,16384 ; B bufs @32768,49152,65536
    int mblk, pnl;
    {
        int bid = blockIdx.x;
        int x = bid & 7, j = bid >> 3;
        int pw = GN >> 3;
        int whole = pw * 128;
        if (bid < whole) { pnl = x + 8 * (j >> 4); mblk = j & 15; }
        else { int r = bid - whole; pnl = (pw << 3) + (r >> 4); mblk = r & 15; }
    }
    const int m0 = mblk * 128;
    const int n0 = pnl * 128;
    const int t    = threadIdx.x;
    const int lane = t & 63;
    const int wave = t >> 6;
    const int wm = (wave >> 1) * 64;
    const int wn = (wave & 1) * 64;

    f32x4 acc[4][4];
    #pragma unroll
    for (int i = 0; i < 4; ++i)
        #pragma unroll
        for (int j = 0; j < 4; ++j) {
            acc[i][j][0] = 0.f; acc[i][j][1] = 0.f; acc[i][j][2] = 0.f; acc[i][j][3] = 0.f;
        }

    const int l8 = lane >> 3;
    const int lc = (lane & 7) ^ l8;
    const __hip_bfloat16* agp[4];
    const __hip_bfloat16* bgp[4];
    int aoff[4];
    int boff[4];
    #pragma unroll
    for (int i = 0; i < 4; ++i) {
        int row = wave * 32 + i * 8 + l8;
        agp[i]  = A + (size_t)(m0 + row) * K + lc * 8;
        aoff[i] = (wave * 32 + i * 8) * 128;
        bgp[i]  = Bt + (size_t)(n0 + row) * K + lc * 8;
        boff[i] = (wave * 32 + i * 8) * 128;
    }

    int a0 = 0,     a1 = 16384;
    int b0 = 32768, b1 = 49152, b2 = 65536;

    // ---- prologue: A(0), B(0), B(1) ----
    #pragma unroll
    for (int i = 0; i < 4; ++i) gload16(agp[i], smem + a0 + aoff[i]);
    #pragma unroll
    for (int i = 0; i < 4; ++i) gload16(bgp[i], smem + b0 + boff[i]);
    if (64 < K) {
        #pragma unroll
        for (int i = 0; i < 4; ++i) gload16(bgp[i] + 64, smem + b1 + boff[i]);
    }

    for (int k0 = 0; k0 < K; k0 += 64) {
        // queue (oldest first): B(t), A(t), B(t+1) -> wait-4 drains B(t),A(t)
        if (k0 + 64 < K) { WAITV4(); } else { WAITV0(); }
        __builtin_amdgcn_s_barrier();
        if (k0 + 64 < K) {     // A(t+1), 1-ahead (into barrier-freed buffer)
            #pragma unroll
            for (int i = 0; i < 4; ++i) gload16(agp[i] + k0 + 64, smem + a1 + aoff[i]);
        }
        if (k0 + 128 < K) {    // B(t+2), 2-ahead
            #pragma unroll
            for (int i = 0; i < 4; ++i) gload16(bgp[i] + k0 + 128, smem + b2 + boff[i]);
        }
        const unsigned char* abuf = smem + a0;
        const unsigned char* bbuf = smem + b0;
        const int lr = lane & 15;
        const int lk = lane >> 4;
        #pragma unroll
        for (int ks = 0; ks < 2; ++ks) {
            int chunk = ks * 4 + lk;
            short8 af[4], bfr[4];
            #pragma unroll
            for (int m = 0; m < 4; ++m) {
                int row = wm + m * 16 + lr;
                af[m] = *(const short8*)(abuf + row * 128 + ((chunk * 16) ^ ((row & 7) << 4)));
            }
            #pragma unroll
            for (int n = 0; n < 4; ++n) {
                int nn = wn + n * 16 + lr;
                bfr[n] = *(const short8*)(bbuf + nn * 128 + ((chunk * 16) ^ ((nn & 7) << 4)));
            }
            #pragma unroll
            for (int m = 0; m < 4; ++m)
                #pragma unroll
                for (int n = 0; n < 4; ++n)
                    acc[m][n] = __builtin_amdgcn_mfma_f32_16x16x32_bf16(af[m], bfr[n], acc[m][n], 0, 0, 0);
        }
        // rotate: A swap; B 3-cycle
        int ta = a0; a0 = a1; a1 = ta;
        int tb = b0; b0 = b1; b1 = b2; b2 = tb;
    }

    const int lr = lane & 15;
    const int lq = lane >> 4;
    #pragma unroll
    for (int m = 0; m < 4; ++m) {
        int rbase = m0 + wm + m * 16 + lq * 4;
        #pragma unroll
        for (int j = 0; j < 4; ++j) {
            int row = rbase + j;
            #pragma unroll
            for (int n = 0; n < 4; ++n) {
                int col = n0 + wn + n * 16 + lr;
                __builtin_nontemporal_store(acc[m][n][j],
                    Cout + (size_t)row * N + col);
            }
        }
    }
}

// ---------------------------------------------------------------------------
// MFMA causal attention (r25-r27, proven)
// ---------------------------------------------------------------------------
__global__ __launch_bounds__(256)
void attn_mfma(const __hip_bfloat16* __restrict__ qkv,
               __hip_bfloat16* __restrict__ y)
{
    __shared__ short Qs[64][72];
    __shared__ short Ps[64][72];
    __shared__ unsigned char Kl[8192];
    __shared__ short Vt[64][72];

    const int bid = blockIdx.x;
    const int p   = bid >> 5;
    const int qt  = (p < 8) ? (15 - 2 * p) : (2 * (p - 8));
    const int bh  = bid & 31;
    const int b = bh >> 4, h = bh & 15;
    const int t = threadIdx.x, lane = t & 63, w = t >> 6;
    const int lr = lane & 15, lg = lane >> 4;
    const size_t base = (size_t)b * 1024 * 3072;
    const int qbase = qt * 64;

    {
        int row = t >> 2, c = t & 3;
        const short8* qsrc = (const short8*)(qkv + base + (size_t)(qbase + row) * 3072 + h * 64);
        *(short8*)&Qs[row][c * 8]      = qsrc[c];
        *(short8*)&Qs[row][c * 8 + 32] = qsrc[c + 4];
    }
    __syncthreads();

    short8 aq0 = *(const short8*)&Qs[w * 16 + lr][0 * 32 + lg * 8];
    short8 aq1 = *(const short8*)&Qs[w * 16 + lr][1 * 32 + lg * 8];

    f32x4 oacc[4];
    #pragma unroll
    for (int dt = 0; dt < 4; ++dt) { oacc[dt][0]=0.f; oacc[dt][1]=0.f; oacc[dt][2]=0.f; oacc[dt][3]=0.f; }
    float lsum[4] = {0.f, 0.f, 0.f, 0.f};

    const int ntiles = qt + 1;
    const int kkey = t >> 2, kc = t & 3;
    const int vkey = t & 63, vc = t >> 6;

    short8 rk0, rk1, rv0, rv1;
    {
        const short8* ksrc = (const short8*)(qkv + base + (size_t)kkey * 3072 + 1024 + h * 64);
        rk0 = ksrc[kc]; rk1 = ksrc[kc + 4];
        const short8* vsrc = (const short8*)(qkv + base + (size_t)vkey * 3072 + 2048 + h * 64);
        rv0 = vsrc[vc]; rv1 = vsrc[vc + 4];
    }
    {
        int rb = kkey * 128, sw = (kkey & 7) << 4;
        *(short8*)(Kl + rb + ((kc * 16) ^ sw)) = rk0;
        *(short8*)(Kl + rb + (((kc + 4) * 16) ^ sw)) = rk1;
        #pragma unroll
        for (int j = 0; j < 8; ++j) Vt[vc * 8 + j][vkey] = rv0[j];
        #pragma unroll
        for (int j = 0; j < 8; ++j) Vt[(vc + 4) * 8 + j][vkey] = rv1[j];
    }
    __syncthreads();

    for (int tile = 0; tile < ntiles; ++tile) {
        if (tile + 1 < ntiles) {
            const int kb2 = (tile + 1) * 64;
            const short8* ksrc = (const short8*)(qkv + base + (size_t)(kb2 + kkey) * 3072 + 1024 + h * 64);
            rk0 = ksrc[kc]; rk1 = ksrc[kc + 4];
            const short8* vsrc = (const short8*)(qkv + base + (size_t)(kb2 + vkey) * 3072 + 2048 + h * 64);
            rv0 = vsrc[vc]; rv1 = vsrc[vc + 4];
        }

        const int kb = tile * 64;
        f32x4 sacc[4];
        #pragma unroll
        for (int kt = 0; kt < 4; ++kt) { sacc[kt][0]=0.f; sacc[kt][1]=0.f; sacc[kt][2]=0.f; sacc[kt][3]=0.f; }
        #pragma unroll
        for (int ks = 0; ks < 2; ++ks) {
            short8 aq = ks ? aq1 : aq0;
            #pragma unroll
            for (int kt = 0; kt < 4; ++kt) {
                int krow = kt * 16 + lr;
                short8 bk = *(const short8*)(Kl + krow * 128 + (((ks * 4 + lg) * 16) ^ ((krow & 7) << 4)));
                sacc[kt] = __builtin_amdgcn_mfma_f32_16x16x32_bf16(aq, bk, sacc[kt], 0, 0, 0);
            }
        }

        #pragma unroll
        for (int kt = 0; kt < 4; ++kt) {
            int key = kb + kt * 16 + lr;
            #pragma unroll
            for (int j = 0; j < 4; ++j) {
                int q = qbase + w * 16 + lg * 4 + j;
                float pv = (key <= q) ? __expf(sacc[kt][j] * 0.125f) : 0.f;
                lsum[j] += pv;
                Ps[w * 16 + lg * 4 + j][kt * 16 + lr] = (short)f2bf(pv);
            }
        }

        #pragma unroll
        for (int ks = 0; ks < 2; ++ks) {
            short8 ap = *(const short8*)&Ps[w * 16 + lr][ks * 32 + lg * 8];
            #pragma unroll
            for (int dt = 0; dt < 4; ++dt) {
                short8 bv = *(const short8*)&Vt[dt * 16 + lr][ks * 32 + lg * 8];
                oacc[dt] = __builtin_amdgcn_mfma_f32_16x16x32_bf16(ap, bv, oacc[dt], 0, 0, 0);
            }
        }

        if (tile + 1 < ntiles) {
            __syncthreads();
            int rb = kkey * 128, sw = (kkey & 7) << 4;
            *(short8*)(Kl + rb + ((kc * 16) ^ sw)) = rk0;
            *(short8*)(Kl + rb + (((kc + 4) * 16) ^ sw)) = rk1;
            #pragma unroll
            for (int j = 0; j < 8; ++j) Vt[vc * 8 + j][vkey] = rv0[j];
            #pragma unroll
            for (int j = 0; j < 8; ++j) Vt[(vc + 4) * 8 + j][vkey] = rv1[j];
            __syncthreads();
        }
    }

    #pragma unroll
    for (int j = 0; j < 4; ++j) {
        float l = lsum[j];
        l += __shfl_xor(l, 1); l += __shfl_xor(l, 2);
        l += __shfl_xor(l, 4); l += __shfl_xor(l, 8);
        float inv = 1.f / l;
        int qrow = qbase + w * 16 + lg * 4 + j;
        __hip_bfloat16* dst = y + (size_t)(b * 1024 + qrow) * 1024 + h * 64;
        #pragma unroll
        for (int dt = 0; dt < 4; ++dt)
            dst[dt * 16 + lr] = __float2bfloat16(oacc[dt][j] * inv);
    }
}

// ---------------------------------------------------------------------------
// Host launch: layer GEMMs on p3 BN=64 (r26-best), LM head on mixed-depth
// counted-vmcnt BN=128 (new). Attention/LN/embed/tc unchanged.
// ---------------------------------------------------------------------------
extern "C" void kernel_launch(void* const* d_in, const int* in_sizes, int n_in,
                              void* d_out, int out_size, void* d_ws, size_t ws_size,
                              hipStream_t stream)
{
    (void)in_sizes; (void)n_in; (void)out_size; (void)ws_size;

    const int*   ids    = (const int*)d_in[0];
    const float* wte    = (const float*)d_in[1];
    const float* wpe    = (const float*)d_in[2];
    const float* ln1_g  = (const float*)d_in[3];
    const float* ln1_b  = (const float*)d_in[4];
    const float* w_qkv  = (const float*)d_in[5];
    const float* b_qkv  = (const float*)d_in[6];
    const float* w_proj = (const float*)d_in[7];
    const float* b_proj = (const float*)d_in[8];
    const float* ln2_g  = (const float*)d_in[9];
    const float* ln2_b  = (const float*)d_in[10];
    const float* w_fc1  = (const float*)d_in[11];
    const float* b_fc1  = (const float*)d_in[12];
    const float* w_fc2  = (const float*)d_in[13];
    const float* b_fc2  = (const float*)d_in[14];
    const float* lnf_g  = (const float*)d_in[15];
    const float* lnf_b  = (const float*)d_in[16];
    const float* w_lm   = (const float*)d_in[17];

    char* ws = (char*)d_ws;
    __hip_bfloat16* abuf_bf = (__hip_bfloat16*)ws;                    // 4 MB
    float*          hbuf    = (float*)(ws + (4u<<20));                // 8 MB
    __hip_bfloat16* qkvb_bf = (__hip_bfloat16*)(ws + (12u<<20));      // 12 MB
    __hip_bfloat16* ybuf_bf = (__hip_bfloat16*)(ws + (24u<<20));      // 4 MB
    __hip_bfloat16* mbuf_bf = (__hip_bfloat16*)(ws + (28u<<20));      // 16 MB
    __hip_bfloat16* wlm_bf  = (__hip_bfloat16*)(ws + (4u<<20));       // 65.5 MB (end)

    __hip_bfloat16* wq_bf = (__hip_bfloat16*)d_out;
    __hip_bfloat16* wp_bf = wq_bf + (size_t)4*1024*3072;
    __hip_bfloat16* w1_bf = wp_bf + (size_t)4*1024*1024;
    __hip_bfloat16* w2_bf = w1_bf + (size_t)4*1024*4096;

    float* out = (float*)d_out;   // f32 logits

    tc_kernel<<<dim3(16, 48, 4), 256, 0, stream>>>(w_qkv,  wq_bf, 3072, 1024);
    tc_kernel<<<dim3(16, 16, 4), 256, 0, stream>>>(w_proj, wp_bf, 1024, 1024);
    tc_kernel<<<dim3(16, 64, 4), 256, 0, stream>>>(w_fc1,  w1_bf, 4096, 1024);
    tc_kernel<<<dim3(64, 16, 4), 256, 0, stream>>>(w_fc2,  w2_bf, 1024, 4096);

    embed_kernel<<<2048, 256, 0, stream>>>(ids, wte, wpe, hbuf);

    for (int l = 0; l < 4; ++l) {
        ln_kernel<<<2048, 256, 0, stream>>>(hbuf, ln1_g + l*1024, ln1_b + l*1024, abuf_bf);
        gemm_p3<true,false><<<16*48, 256, 0, stream>>>(
            abuf_bf, wq_bf + (size_t)l*1024*3072, b_qkv + l*3072, nullptr, qkvb_bf, 2048, 3072, 1024, 48);
        attn_mfma<<<512, 256, 0, stream>>>(qkvb_bf, ybuf_bf);
        gemm_p3<false,false><<<16*16, 256, 0, stream>>>(
            ybuf_bf, wp_bf + (size_t)l*1024*1024, b_proj + l*1024, hbuf, hbuf, 2048, 1024, 1024, 16);
        ln_kernel<<<2048, 256, 0, stream>>>(hbuf, ln2_g + l*1024, ln2_b + l*1024, abuf_bf);
        gemm_p3<true,true><<<16*64, 256, 0, stream>>>(
            abuf_bf, w1_bf + (size_t)l*1024*4096, b_fc1 + l*4096, nullptr, mbuf_bf, 2048, 4096, 1024, 64);
        gemm_p3<false,false><<<16*16, 256, 0, stream>>>(
            mbuf_bf, w2_bf + (size_t)l*4096*1024, b_fc2 + l*1024, hbuf, hbuf, 2048, 1024, 4096, 16);
    }

    ln_kernel<<<2048, 256, 0, stream>>>(hbuf, lnf_g, lnf_b, abuf_bf);
    tc_kernel<<<dim3(16, 500, 1), 256, 0, stream>>>(w_lm, wlm_bf, 32000, 1024);
    gemm_lm3<<<16*250, 256, 0, stream>>>(
        abuf_bf, wlm_bf, out, 2048, 32000, 1024, 250);
}

// Round 29
// 816.448 us; speedup vs baseline: 1.0069x; 1.0069x over previous
//
#include <hip/hip_runtime.h>
#include <hip/hip_bf16.h>
#include <math.h>

typedef __attribute__((ext_vector_type(4))) float f32x4;
typedef __attribute__((ext_vector_type(8))) short short8;
typedef __attribute__((ext_vector_type(4))) unsigned short ushort4v;

__device__ __forceinline__ unsigned short f2bf(float f) {
    return __builtin_bit_cast(unsigned short, __float2bfloat16(f));
}

__device__ __forceinline__ void gload16(const void* g, void* l) {
    __builtin_amdgcn_global_load_lds(
        (const __attribute__((address_space(1))) unsigned int*)g,
        (__attribute__((address_space(3))) unsigned int*)l, 16, 0, 0);
}

#define WAITV6() asm volatile("s_waitcnt vmcnt(6)" ::: "memory")
#define WAITV0() asm volatile("s_waitcnt vmcnt(0)" ::: "memory")

// ---------------------------------------------------------------------------
// Transpose-cast: in f32 [K][N] (layer z) -> out bf16 [N][K] (k-contiguous)
// ---------------------------------------------------------------------------
__global__ __launch_bounds__(256)
void tc_kernel(const float* __restrict__ in, __hip_bfloat16* __restrict__ out,
               int N, int K)
{
    __shared__ float tile[64][65];
    const size_t loff = (size_t)blockIdx.z * K * N;
    const int k0 = blockIdx.x * 64, n0 = blockIdx.y * 64;
    const int t = threadIdx.x;
    {
        int kk = t >> 2, nb = (t & 3) * 16;
        const float* src = in + loff + (size_t)(k0 + kk) * N + n0 + nb;
        #pragma unroll
        for (int j = 0; j < 4; ++j) {
            float4 v = *(const float4*)(src + j * 4);
            tile[kk][nb + j*4 + 0] = v.x; tile[kk][nb + j*4 + 1] = v.y;
            tile[kk][nb + j*4 + 2] = v.z; tile[kk][nb + j*4 + 3] = v.w;
        }
    }
    __syncthreads();
    {
        int nn = t >> 2, kb = (t & 3) * 16;
        __hip_bfloat16* dst = out + loff + (size_t)(n0 + nn) * K + k0 + kb;
        short8 w0, w1;
        #pragma unroll
        for (int j = 0; j < 8; ++j) w0[j] = (short)f2bf(tile[kb + j][nn]);
        #pragma unroll
        for (int j = 0; j < 8; ++j) w1[j] = (short)f2bf(tile[kb + 8 + j][nn]);
        *(short8*)dst = w0;
        *(short8*)(dst + 8) = w1;
    }
}

// ---------------------------------------------------------------------------
// Embedding (f32 out)
// ---------------------------------------------------------------------------
__global__ __launch_bounds__(256)
void embed_kernel(const int* __restrict__ ids, const float* __restrict__ wte,
                  const float* __restrict__ wpe, float* __restrict__ h)
{
    int row  = blockIdx.x;
    int tpos = row & 1023;
    int id   = ids[row];
    float4 a = ((const float4*)(wte + (size_t)id * 1024))[threadIdx.x];
    float4 p = ((const float4*)(wpe + (size_t)tpos * 1024))[threadIdx.x];
    float4 o; o.x = a.x + p.x; o.y = a.y + p.y; o.z = a.z + p.z; o.w = a.w + p.w;
    ((float4*)(h + (size_t)row * 1024))[threadIdx.x] = o;
}

// ---------------------------------------------------------------------------
// LayerNorm: f32 in, BF16 out
// ---------------------------------------------------------------------------
__global__ __launch_bounds__(256)
void ln_kernel(const float* __restrict__ x, const float* __restrict__ g,
               const float* __restrict__ b, __hip_bfloat16* __restrict__ out)
{
    size_t row = blockIdx.x;
    float4 v = ((const float4*)(x + row * 1024))[threadIdx.x];
    float s  = v.x + v.y + v.z + v.w;
    float s2 = v.x*v.x + v.y*v.y + v.z*v.z + v.w*v.w;
    #pragma unroll
    for (int off = 32; off; off >>= 1) {
        s  += __shfl_xor(s, off);
        s2 += __shfl_xor(s2, off);
    }
    __shared__ float rs[4], rs2[4];
    int wave = threadIdx.x >> 6;
    if ((threadIdx.x & 63) == 0) { rs[wave] = s; rs2[wave] = s2; }
    __syncthreads();
    s  = rs[0] + rs[1] + rs[2] + rs[3];
    s2 = rs2[0] + rs2[1] + rs2[2] + rs2[3];
    float mean = s * (1.f / 1024.f);
    float var  = s2 * (1.f / 1024.f) - mean * mean;
    float rstd = rsqrtf(var + 1e-5f);
    float4 gg = ((const float4*)g)[threadIdx.x];
    float4 bb = ((const float4*)b)[threadIdx.x];
    ushort4v ov;
    ov[0] = f2bf((v.x - mean) * rstd * gg.x + bb.x);
    ov[1] = f2bf((v.y - mean) * rstd * gg.y + bb.y);
    ov[2] = f2bf((v.z - mean) * rstd * gg.z + bb.z);
    ov[3] = f2bf((v.w - mean) * rstd * gg.w + bb.w);
    ((ushort4v*)(out + row * 1024))[threadIdx.x] = ov;
}

// ---------------------------------------------------------------------------
// Layer GEMM (r26/r27, proven): 3-deep counted-vmcnt pipeline, BN=64.
// ---------------------------------------------------------------------------
template<bool OUT_BF16, bool GELU_ACT>
__global__ __launch_bounds__(256)
void gemm_p3(const __hip_bfloat16* __restrict__ A,
             const __hip_bfloat16* __restrict__ Bt,
             const float* __restrict__ bias, const float* __restrict__ resid,
             void* __restrict__ Cout, int M, int N, int K, int GN)
{
    __shared__ unsigned char smem[73728];
    int mblk, pnl;
    {
        int bid = blockIdx.x;
        int x = bid & 7, j = bid >> 3;
        int pw = GN >> 3;
        int whole = pw * 128;
        if (bid < whole) { pnl = x + 8 * (j >> 4); mblk = j & 15; }
        else { int r = bid - whole; pnl = (pw << 3) + (r >> 4); mblk = r & 15; }
    }
    const int m0 = mblk * 128;
    const int n0 = pnl * 64;
    const int t    = threadIdx.x;
    const int lane = t & 63;
    const int wave = t >> 6;
    const int wm = (wave & 1) * 64;
    const int wn = (wave >> 1) * 32;

    f32x4 acc[4][2];
    #pragma unroll
    for (int i = 0; i < 4; ++i)
        #pragma unroll
        for (int j = 0; j < 2; ++j) {
            acc[i][j][0] = 0.f; acc[i][j][1] = 0.f; acc[i][j][2] = 0.f; acc[i][j][3] = 0.f;
        }

    const int l8 = lane >> 3;
    const int lc = (lane & 7) ^ l8;
    const __hip_bfloat16* agp[4];
    const __hip_bfloat16* bgp[2];
    int aoff[4];
    int boff[2];
    #pragma unroll
    for (int i = 0; i < 4; ++i) {
        int row = wave * 32 + i * 8 + l8;
        agp[i]  = A + (size_t)(m0 + row) * K + lc * 8;
        aoff[i] = (wave * 32 + i * 8) * 128;
    }
    #pragma unroll
    for (int i = 0; i < 2; ++i) {
        int row = wave * 16 + i * 8 + l8;
        bgp[i]  = Bt + (size_t)(n0 + row) * K + lc * 8;
        boff[i] = (wave * 16 + i * 8) * 128;
    }

    int a0 = 0,     a1 = 16384, a2 = 32768;
    int b0 = 49152, b1 = 57344, b2 = 65536;

    #pragma unroll
    for (int i = 0; i < 4; ++i) gload16(agp[i], smem + a0 + aoff[i]);
    #pragma unroll
    for (int i = 0; i < 2; ++i) gload16(bgp[i], smem + b0 + boff[i]);
    if (64 < K) {
        #pragma unroll
        for (int i = 0; i < 4; ++i) gload16(agp[i] + 64, smem + a1 + aoff[i]);
        #pragma unroll
        for (int i = 0; i < 2; ++i) gload16(bgp[i] + 64, smem + b1 + boff[i]);
    }

    for (int k0 = 0; k0 < K; k0 += 64) {
        if (k0 + 64 < K) { WAITV6(); } else { WAITV0(); }
        __builtin_amdgcn_s_barrier();
        if (k0 + 128 < K) {
            #pragma unroll
            for (int i = 0; i < 4; ++i) gload16(agp[i] + k0 + 128, smem + a2 + aoff[i]);
            #pragma unroll
            for (int i = 0; i < 2; ++i) gload16(bgp[i] + k0 + 128, smem + b2 + boff[i]);
        }
        const unsigned char* abuf = smem + a0;
        const unsigned char* bbuf = smem + b0;
        const int lr = lane & 15;
        const int lk = lane >> 4;
        #pragma unroll
        for (int ks = 0; ks < 2; ++ks) {
            int chunk = ks * 4 + lk;
            short8 af[4], bfr[2];
            #pragma unroll
            for (int m = 0; m < 4; ++m) {
                int row = wm + m * 16 + lr;
                af[m] = *(const short8*)(abuf + row * 128 + ((chunk * 16) ^ ((row & 7) << 4)));
            }
            #pragma unroll
            for (int n = 0; n < 2; ++n) {
                int nn = wn + n * 16 + lr;
                bfr[n] = *(const short8*)(bbuf + nn * 128 + ((chunk * 16) ^ ((nn & 7) << 4)));
            }
            #pragma unroll
            for (int m = 0; m < 4; ++m)
                #pragma unroll
                for (int n = 0; n < 2; ++n)
                    acc[m][n] = __builtin_amdgcn_mfma_f32_16x16x32_bf16(af[m], bfr[n], acc[m][n], 0, 0, 0);
        }
        int ta = a0; a0 = a1; a1 = a2; a2 = ta;
        int tb = b0; b0 = b1; b1 = b2; b2 = tb;
    }

    const int lr = lane & 15;
    const int lq = lane >> 4;
    float bv[2];
    #pragma unroll
    for (int n = 0; n < 2; ++n)
        bv[n] = bias ? bias[n0 + wn + n * 16 + lr] : 0.f;
    #pragma unroll
    for (int m = 0; m < 4; ++m) {
        int rbase = m0 + wm + m * 16 + lq * 4;
        #pragma unroll
        for (int j = 0; j < 4; ++j) {
            int row = rbase + j;
            #pragma unroll
            for (int n = 0; n < 2; ++n) {
                int col = n0 + wn + n * 16 + lr;
                float v = acc[m][n][j] + bv[n];
                if (resid) v += resid[(size_t)row * N + col];
                if (GELU_ACT) v = 0.5f * v * (1.f + erff(v * 0.70710678118654752f));
                if (OUT_BF16)
                    ((__hip_bfloat16*)Cout)[(size_t)row * N + col] = __float2bfloat16(v);
                else
                    ((float*)Cout)[(size_t)row * N + col] = v;
            }
        }
    }
}

// ---------------------------------------------------------------------------
// LM-head GEMM (r25/r27, proven best: 155us): dbuf staging + panel swizzle,
// BM=128 BN=128, NT f32 stores.
// ---------------------------------------------------------------------------
__global__ __launch_bounds__(256)
void gemm_db_nt(const __hip_bfloat16* __restrict__ A,
                const __hip_bfloat16* __restrict__ Bt,
                float* __restrict__ Cout, int M, int N, int K, int GN)
{
    __shared__ unsigned char smem[65536];
    int mblk, pnl;
    {
        int bid = blockIdx.x;
        int x = bid & 7, j = bid >> 3;
        int pw = GN >> 3;
        int whole = pw * 128;
        if (bid < whole) { pnl = x + 8 * (j >> 4); mblk = j & 15; }
        else { int r = bid - whole; pnl = (pw << 3) + (r >> 4); mblk = r & 15; }
    }
    const int m0 = mblk * 128;
    const int n0 = pnl * 128;
    const int t    = threadIdx.x;
    const int lane = t & 63;
    const int wave = t >> 6;
    const int wm = (wave >> 1) * 64;
    const int wn = (wave & 1) * 64;

    f32x4 acc[4][4];
    #pragma unroll
    for (int i = 0; i < 4; ++i)
        #pragma unroll
        for (int j = 0; j < 4; ++j) {
            acc[i][j][0] = 0.f; acc[i][j][1] = 0.f; acc[i][j][2] = 0.f; acc[i][j][3] = 0.f;
        }

    const int l8 = lane >> 3;
    const int lc = (lane & 7) ^ l8;
    const __hip_bfloat16* agp[4];
    const __hip_bfloat16* bgp[4];
    int aoff[4];
    int boff[4];
    #pragma unroll
    for (int i = 0; i < 4; ++i) {
        int row = wave * 32 + i * 8 + l8;
        agp[i]  = A + (size_t)(m0 + row) * K + lc * 8;
        aoff[i] = (wave * 32 + i * 8) * 128;
        bgp[i]  = Bt + (size_t)(n0 + row) * K + lc * 8;
        boff[i] = (wave * 32 + i * 8) * 128;
    }
    const int aBufOff[2] = { 0, 16384 };
    const int bBufOff[2] = { 32768, 49152 };

    #pragma unroll
    for (int i = 0; i < 4; ++i) gload16(agp[i], smem + aBufOff[0] + aoff[i]);
    #pragma unroll
    for (int i = 0; i < 4; ++i) gload16(bgp[i], smem + bBufOff[0] + boff[i]);
    __syncthreads();

    int cur = 0;
    for (int k0 = 0; k0 < K; k0 += 64) {
        if (k0 + 64 < K) {
            #pragma unroll
            for (int i = 0; i < 4; ++i)
                gload16(agp[i] + k0 + 64, smem + aBufOff[cur ^ 1] + aoff[i]);
            #pragma unroll
            for (int i = 0; i < 4; ++i)
                gload16(bgp[i] + k0 + 64, smem + bBufOff[cur ^ 1] + boff[i]);
        }
        const unsigned char* abuf = smem + aBufOff[cur];
        const unsigned char* bbuf = smem + bBufOff[cur];
        const int lr = lane & 15;
        const int lk = lane >> 4;
        #pragma unroll
        for (int ks = 0; ks < 2; ++ks) {
            int chunk = ks * 4 + lk;
            short8 af[4], bfr[4];
            #pragma unroll
            for (int m = 0; m < 4; ++m) {
                int row = wm + m * 16 + lr;
                af[m] = *(const short8*)(abuf + row * 128 + ((chunk * 16) ^ ((row & 7) << 4)));
            }
            #pragma unroll
            for (int n = 0; n < 4; ++n) {
                int nn = wn + n * 16 + lr;
                bfr[n] = *(const short8*)(bbuf + nn * 128 + ((chunk * 16) ^ ((nn & 7) << 4)));
            }
            #pragma unroll
            for (int m = 0; m < 4; ++m)
                #pragma unroll
                for (int n = 0; n < 4; ++n)
                    acc[m][n] = __builtin_amdgcn_mfma_f32_16x16x32_bf16(af[m], bfr[n], acc[m][n], 0, 0, 0);
        }
        __syncthreads();
        cur ^= 1;
    }

    const int lr = lane & 15;
    const int lq = lane >> 4;
    #pragma unroll
    for (int m = 0; m < 4; ++m) {
        int rbase = m0 + wm + m * 16 + lq * 4;
        #pragma unroll
        for (int j = 0; j < 4; ++j) {
            int row = rbase + j;
            #pragma unroll
            for (int n = 0; n < 4; ++n) {
                int col = n0 + wn + n * 16 + lr;
                __builtin_nontemporal_store(acc[m][n][j],
                    Cout + (size_t)row * N + col);
            }
        }
    }
}

// ---------------------------------------------------------------------------
// MFMA causal attention (r25-r27 structure + T5 setprio around MFMA clusters)
// ---------------------------------------------------------------------------
__global__ __launch_bounds__(256)
void attn_mfma(const __hip_bfloat16* __restrict__ qkv,
               __hip_bfloat16* __restrict__ y)
{
    __shared__ short Qs[64][72];
    __shared__ short Ps[64][72];
    __shared__ unsigned char Kl[8192];
    __shared__ short Vt[64][72];

    const int bid = blockIdx.x;
    const int p   = bid >> 5;
    const int qt  = (p < 8) ? (15 - 2 * p) : (2 * (p - 8));
    const int bh  = bid & 31;
    const int b = bh >> 4, h = bh & 15;
    const int t = threadIdx.x, lane = t & 63, w = t >> 6;
    const int lr = lane & 15, lg = lane >> 4;
    const size_t base = (size_t)b * 1024 * 3072;
    const int qbase = qt * 64;

    {
        int row = t >> 2, c = t & 3;
        const short8* qsrc = (const short8*)(qkv + base + (size_t)(qbase + row) * 3072 + h * 64);
        *(short8*)&Qs[row][c * 8]      = qsrc[c];
        *(short8*)&Qs[row][c * 8 + 32] = qsrc[c + 4];
    }
    __syncthreads();

    short8 aq0 = *(const short8*)&Qs[w * 16 + lr][0 * 32 + lg * 8];
    short8 aq1 = *(const short8*)&Qs[w * 16 + lr][1 * 32 + lg * 8];

    f32x4 oacc[4];
    #pragma unroll
    for (int dt = 0; dt < 4; ++dt) { oacc[dt][0]=0.f; oacc[dt][1]=0.f; oacc[dt][2]=0.f; oacc[dt][3]=0.f; }
    float lsum[4] = {0.f, 0.f, 0.f, 0.f};

    const int ntiles = qt + 1;
    const int kkey = t >> 2, kc = t & 3;
    const int vkey = t & 63, vc = t >> 6;

    short8 rk0, rk1, rv0, rv1;
    {
        const short8* ksrc = (const short8*)(qkv + base + (size_t)kkey * 3072 + 1024 + h * 64);
        rk0 = ksrc[kc]; rk1 = ksrc[kc + 4];
        const short8* vsrc = (const short8*)(qkv + base + (size_t)vkey * 3072 + 2048 + h * 64);
        rv0 = vsrc[vc]; rv1 = vsrc[vc + 4];
    }
    {
        int rb = kkey * 128, sw = (kkey & 7) << 4;
        *(short8*)(Kl + rb + ((kc * 16) ^ sw)) = rk0;
        *(short8*)(Kl + rb + (((kc + 4) * 16) ^ sw)) = rk1;
        #pragma unroll
        for (int j = 0; j < 8; ++j) Vt[vc * 8 + j][vkey] = rv0[j];
        #pragma unroll
        for (int j = 0; j < 8; ++j) Vt[(vc + 4) * 8 + j][vkey] = rv1[j];
    }
    __syncthreads();

    for (int tile = 0; tile < ntiles; ++tile) {
        if (tile + 1 < ntiles) {
            const int kb2 = (tile + 1) * 64;
            const short8* ksrc = (const short8*)(qkv + base + (size_t)(kb2 + kkey) * 3072 + 1024 + h * 64);
            rk0 = ksrc[kc]; rk1 = ksrc[kc + 4];
            const short8* vsrc = (const short8*)(qkv + base + (size_t)(kb2 + vkey) * 3072 + 2048 + h * 64);
            rv0 = vsrc[vc]; rv1 = vsrc[vc + 4];
        }

        const int kb = tile * 64;
        f32x4 sacc[4];
        #pragma unroll
        for (int kt = 0; kt < 4; ++kt) { sacc[kt][0]=0.f; sacc[kt][1]=0.f; sacc[kt][2]=0.f; sacc[kt][3]=0.f; }
        __builtin_amdgcn_s_setprio(1);
        #pragma unroll
        for (int ks = 0; ks < 2; ++ks) {
            short8 aq = ks ? aq1 : aq0;
            #pragma unroll
            for (int kt = 0; kt < 4; ++kt) {
                int krow = kt * 16 + lr;
                short8 bk = *(const short8*)(Kl + krow * 128 + (((ks * 4 + lg) * 16) ^ ((krow & 7) << 4)));
                sacc[kt] = __builtin_amdgcn_mfma_f32_16x16x32_bf16(aq, bk, sacc[kt], 0, 0, 0);
            }
        }
        __builtin_amdgcn_s_setprio(0);

        #pragma unroll
        for (int kt = 0; kt < 4; ++kt) {
            int key = kb + kt * 16 + lr;
            #pragma unroll
            for (int j = 0; j < 4; ++j) {
                int q = qbase + w * 16 + lg * 4 + j;
                float pv = (key <= q) ? __expf(sacc[kt][j] * 0.125f) : 0.f;
                lsum[j] += pv;
                Ps[w * 16 + lg * 4 + j][kt * 16 + lr] = (short)f2bf(pv);
            }
        }

        __builtin_amdgcn_s_setprio(1);
        #pragma unroll
        for (int ks = 0; ks < 2; ++ks) {
            short8 ap = *(const short8*)&Ps[w * 16 + lr][ks * 32 + lg * 8];
            #pragma unroll
            for (int dt = 0; dt < 4; ++dt) {
                short8 bv = *(const short8*)&Vt[dt * 16 + lr][ks * 32 + lg * 8];
                oacc[dt] = __builtin_amdgcn_mfma_f32_16x16x32_bf16(ap, bv, oacc[dt], 0, 0, 0);
            }
        }
        __builtin_amdgcn_s_setprio(0);

        if (tile + 1 < ntiles) {
            __syncthreads();
            int rb = kkey * 128, sw = (kkey & 7) << 4;
            *(short8*)(Kl + rb + ((kc * 16) ^ sw)) = rk0;
            *(short8*)(Kl + rb + (((kc + 4) * 16) ^ sw)) = rk1;
            #pragma unroll
            for (int j = 0; j < 8; ++j) Vt[vc * 8 + j][vkey] = rv0[j];
            #pragma unroll
            for (int j = 0; j < 8; ++j) Vt[(vc + 4) * 8 + j][vkey] = rv1[j];
            __syncthreads();
        }
    }

    #pragma unroll
    for (int j = 0; j < 4; ++j) {
        float l = lsum[j];
        l += __shfl_xor(l, 1); l += __shfl_xor(l, 2);
        l += __shfl_xor(l, 4); l += __shfl_xor(l, 8);
        float inv = 1.f / l;
        int qrow = qbase + w * 16 + lg * 4 + j;
        __hip_bfloat16* dst = y + (size_t)(b * 1024 + qrow) * 1024 + h * 64;
        #pragma unroll
        for (int dt = 0; dt < 4; ++dt)
            dst[dt * 16 + lr] = __float2bfloat16(oacc[dt][j] * inv);
    }
}

// ---------------------------------------------------------------------------
// Host launch: r27 configuration (best measured) + T5 attn setprio.
// ---------------------------------------------------------------------------
extern "C" void kernel_launch(void* const* d_in, const int* in_sizes, int n_in,
                              void* d_out, int out_size, void* d_ws, size_t ws_size,
                              hipStream_t stream)
{
    (void)in_sizes; (void)n_in; (void)out_size; (void)ws_size;

    const int*   ids    = (const int*)d_in[0];
    const float* wte    = (const float*)d_in[1];
    const float* wpe    = (const float*)d_in[2];
    const float* ln1_g  = (const float*)d_in[3];
    const float* ln1_b  = (const float*)d_in[4];
    const float* w_qkv  = (const float*)d_in[5];
    const float* b_qkv  = (const float*)d_in[6];
    const float* w_proj = (const float*)d_in[7];
    const float* b_proj = (const float*)d_in[8];
    const float* ln2_g  = (const float*)d_in[9];
    const float* ln2_b  = (const float*)d_in[10];
    const float* w_fc1  = (const float*)d_in[11];
    const float* b_fc1  = (const float*)d_in[12];
    const float* w_fc2  = (const float*)d_in[13];
    const float* b_fc2  = (const float*)d_in[14];
    const float* lnf_g  = (const float*)d_in[15];
    const float* lnf_b  = (const float*)d_in[16];
    const float* w_lm   = (const float*)d_in[17];

    char* ws = (char*)d_ws;
    __hip_bfloat16* abuf_bf = (__hip_bfloat16*)ws;                    // 4 MB
    float*          hbuf    = (float*)(ws + (4u<<20));                // 8 MB
    __hip_bfloat16* qkvb_bf = (__hip_bfloat16*)(ws + (12u<<20));      // 12 MB
    __hip_bfloat16* ybuf_bf = (__hip_bfloat16*)(ws + (24u<<20));      // 4 MB
    __hip_bfloat16* mbuf_bf = (__hip_bfloat16*)(ws + (28u<<20));      // 16 MB
    __hip_bfloat16* wlm_bf  = (__hip_bfloat16*)(ws + (4u<<20));       // 65.5 MB (end)

    __hip_bfloat16* wq_bf = (__hip_bfloat16*)d_out;
    __hip_bfloat16* wp_bf = wq_bf + (size_t)4*1024*3072;
    __hip_bfloat16* w1_bf = wp_bf + (size_t)4*1024*1024;
    __hip_bfloat16* w2_bf = w1_bf + (size_t)4*1024*4096;

    float* out = (float*)d_out;   // f32 logits

    tc_kernel<<<dim3(16, 48, 4), 256, 0, stream>>>(w_qkv,  wq_bf, 3072, 1024);
    tc_kernel<<<dim3(16, 16, 4), 256, 0, stream>>>(w_proj, wp_bf, 1024, 1024);
    tc_kernel<<<dim3(16, 64, 4), 256, 0, stream>>>(w_fc1,  w1_bf, 4096, 1024);
    tc_kernel<<<dim3(64, 16, 4), 256, 0, stream>>>(w_fc2,  w2_bf, 1024, 4096);

    embed_kernel<<<2048, 256, 0, stream>>>(ids, wte, wpe, hbuf);

    for (int l = 0; l < 4; ++l) {
        ln_kernel<<<2048, 256, 0, stream>>>(hbuf, ln1_g + l*1024, ln1_b + l*1024, abuf_bf);
        gemm_p3<true,false><<<16*48, 256, 0, stream>>>(
            abuf_bf, wq_bf + (size_t)l*1024*3072, b_qkv + l*3072, nullptr, qkvb_bf, 2048, 3072, 1024, 48);
        attn_mfma<<<512, 256, 0, stream>>>(qkvb_bf, ybuf_bf);
        gemm_p3<false,false><<<16*16, 256, 0, stream>>>(
            ybuf_bf, wp_bf + (size_t)l*1024*1024, b_proj + l*1024, hbuf, hbuf, 2048, 1024, 1024, 16);
        ln_kernel<<<2048, 256, 0, stream>>>(hbuf, ln2_g + l*1024, ln2_b + l*1024, abuf_bf);
        gemm_p3<true,true><<<16*64, 256, 0, stream>>>(
            abuf_bf, w1_bf + (size_t)l*1024*4096, b_fc1 + l*4096, nullptr, mbuf_bf, 2048, 4096, 1024, 64);
        gemm_p3<false,false><<<16*16, 256, 0, stream>>>(
            mbuf_bf, w2_bf + (size_t)l*4096*1024, b_fc2 + l*1024, hbuf, hbuf, 2048, 1024, 4096, 16);
    }

    ln_kernel<<<2048, 256, 0, stream>>>(hbuf, lnf_g, lnf_b, abuf_bf);
    tc_kernel<<<dim3(16, 500, 1), 256, 0, stream>>>(w_lm, wlm_bf, 32000, 1024);
    gemm_db_nt<<<16*250, 256, 0, stream>>>(
        abuf_bf, wlm_bf, out, 2048, 32000, 1024, 250);
}

// Round 30
// 816.429 us; speedup vs baseline: 1.0069x; 1.0000x over previous
//
#include <hip/hip_runtime.h>
#include <hip/hip_bf16.h>
#include <math.h>

typedef __attribute__((ext_vector_type(4))) float f32x4;
typedef __attribute__((ext_vector_type(8))) short short8;
typedef __attribute__((ext_vector_type(4))) unsigned short ushort4v;

__device__ __forceinline__ unsigned short f2bf(float f) {
    return __builtin_bit_cast(unsigned short, __float2bfloat16(f));
}

__device__ __forceinline__ void gload16(const void* g, void* l) {
    __builtin_amdgcn_global_load_lds(
        (const __attribute__((address_space(1))) unsigned int*)g,
        (__attribute__((address_space(3))) unsigned int*)l, 16, 0, 0);
}

#define WAITV6() asm volatile("s_waitcnt vmcnt(6)" ::: "memory")
#define WAITV5() asm volatile("s_waitcnt vmcnt(5)" ::: "memory")
#define WAITV0() asm volatile("s_waitcnt vmcnt(0)" ::: "memory")

// ---------------------------------------------------------------------------
// Transpose-cast: in f32 [K][N] (layer z) -> out bf16 [N][K] (k-contiguous)
// ---------------------------------------------------------------------------
__global__ __launch_bounds__(256)
void tc_kernel(const float* __restrict__ in, __hip_bfloat16* __restrict__ out,
               int N, int K)
{
    __shared__ float tile[64][65];
    const size_t loff = (size_t)blockIdx.z * K * N;
    const int k0 = blockIdx.x * 64, n0 = blockIdx.y * 64;
    const int t = threadIdx.x;
    {
        int kk = t >> 2, nb = (t & 3) * 16;
        const float* src = in + loff + (size_t)(k0 + kk) * N + n0 + nb;
        #pragma unroll
        for (int j = 0; j < 4; ++j) {
            float4 v = *(const float4*)(src + j * 4);
            tile[kk][nb + j*4 + 0] = v.x; tile[kk][nb + j*4 + 1] = v.y;
            tile[kk][nb + j*4 + 2] = v.z; tile[kk][nb + j*4 + 3] = v.w;
        }
    }
    __syncthreads();
    {
        int nn = t >> 2, kb = (t & 3) * 16;
        __hip_bfloat16* dst = out + loff + (size_t)(n0 + nn) * K + k0 + kb;
        short8 w0, w1;
        #pragma unroll
        for (int j = 0; j < 8; ++j) w0[j] = (short)f2bf(tile[kb + j][nn]);
        #pragma unroll
        for (int j = 0; j < 8; ++j) w1[j] = (short)f2bf(tile[kb + 8 + j][nn]);
        *(short8*)dst = w0;
        *(short8*)(dst + 8) = w1;
    }
}

// ---------------------------------------------------------------------------
// Embedding (f32 out)
// ---------------------------------------------------------------------------
__global__ __launch_bounds__(256)
void embed_kernel(const int* __restrict__ ids, const float* __restrict__ wte,
                  const float* __restrict__ wpe, float* __restrict__ h)
{
    int row  = blockIdx.x;
    int tpos = row & 1023;
    int id   = ids[row];
    float4 a = ((const float4*)(wte + (size_t)id * 1024))[threadIdx.x];
    float4 p = ((const float4*)(wpe + (size_t)tpos * 1024))[threadIdx.x];
    float4 o; o.x = a.x + p.x; o.y = a.y + p.y; o.z = a.z + p.z; o.w = a.w + p.w;
    ((float4*)(h + (size_t)row * 1024))[threadIdx.x] = o;
}

// ---------------------------------------------------------------------------
// LayerNorm: f32 in, BF16 out
// ---------------------------------------------------------------------------
__global__ __launch_bounds__(256)
void ln_kernel(const float* __restrict__ x, const float* __restrict__ g,
               const float* __restrict__ b, __hip_bfloat16* __restrict__ out)
{
    size_t row = blockIdx.x;
    float4 v = ((const float4*)(x + row * 1024))[threadIdx.x];
    float s  = v.x + v.y + v.z + v.w;
    float s2 = v.x*v.x + v.y*v.y + v.z*v.z + v.w*v.w;
    #pragma unroll
    for (int off = 32; off; off >>= 1) {
        s  += __shfl_xor(s, off);
        s2 += __shfl_xor(s2, off);
    }
    __shared__ float rs[4], rs2[4];
    int wave = threadIdx.x >> 6;
    if ((threadIdx.x & 63) == 0) { rs[wave] = s; rs2[wave] = s2; }
    __syncthreads();
    s  = rs[0] + rs[1] + rs[2] + rs[3];
    s2 = rs2[0] + rs2[1] + rs2[2] + rs2[3];
    float mean = s * (1.f / 1024.f);
    float var  = s2 * (1.f / 1024.f) - mean * mean;
    float rstd = rsqrtf(var + 1e-5f);
    float4 gg = ((const float4*)g)[threadIdx.x];
    float4 bb = ((const float4*)b)[threadIdx.x];
    ushort4v ov;
    ov[0] = f2bf((v.x - mean) * rstd * gg.x + bb.x);
    ov[1] = f2bf((v.y - mean) * rstd * gg.y + bb.y);
    ov[2] = f2bf((v.z - mean) * rstd * gg.z + bb.z);
    ov[3] = f2bf((v.w - mean) * rstd * gg.w + bb.w);
    ((ushort4v*)(out + row * 1024))[threadIdx.x] = ov;
}

// ---------------------------------------------------------------------------
// Layer GEMM: 3-deep counted-vmcnt pipeline (r26-proven), BN templated.
// BN=64: 4 waves x (64x32), NB=2, wait vmcnt(6). LDS 72KB.
// BN=32: 4 waves x (64x16), NB=1, wait vmcnt(5). LDS 60KB -> 2 blocks/CU
//        at grid 512 for proj/fc2 (was 256 = 1/CU underfill).
// ---------------------------------------------------------------------------
template<bool OUT_BF16, bool GELU_ACT, int BN>
__global__ __launch_bounds__(256)
void gemm_p3(const __hip_bfloat16* __restrict__ A,
             const __hip_bfloat16* __restrict__ Bt,
             const float* __restrict__ bias, const float* __restrict__ resid,
             void* __restrict__ Cout, int M, int N, int K, int GN)
{
    constexpr int NF = BN / 32;            // n-frags per wave (2 or 1)
    constexpr int NB = NF;                 // B gloads per thread per tile
    constexpr int BB = BN * 128;           // B buffer bytes
    __shared__ unsigned char smem[49152 + 3 * BB];
    int mblk, pnl;
    {
        int bid = blockIdx.x;
        int x = bid & 7, j = bid >> 3;
        int pw = GN >> 3;
        int whole = pw * 128;
        if (bid < whole) { pnl = x + 8 * (j >> 4); mblk = j & 15; }
        else { int r = bid - whole; pnl = (pw << 3) + (r >> 4); mblk = r & 15; }
    }
    const int m0 = mblk * 128;
    const int n0 = pnl * BN;
    const int t    = threadIdx.x;
    const int lane = t & 63;
    const int wave = t >> 6;
    const int wm = (wave & 1) * 64;
    const int wn = (wave >> 1) * (BN / 2);

    f32x4 acc[4][NF];
    #pragma unroll
    for (int i = 0; i < 4; ++i)
        #pragma unroll
        for (int j = 0; j < NF; ++j) {
            acc[i][j][0] = 0.f; acc[i][j][1] = 0.f; acc[i][j][2] = 0.f; acc[i][j][3] = 0.f;
        }

    const int l8 = lane >> 3;
    const int lc = (lane & 7) ^ l8;
    const __hip_bfloat16* agp[4];
    const __hip_bfloat16* bgp[NB];
    int aoff[4];
    int boff[NB];
    #pragma unroll
    for (int i = 0; i < 4; ++i) {
        int row = wave * 32 + i * 8 + l8;
        agp[i]  = A + (size_t)(m0 + row) * K + lc * 8;
        aoff[i] = (wave * 32 + i * 8) * 128;
    }
    #pragma unroll
    for (int i = 0; i < NB; ++i) {
        int row = wave * (BN / 4) + i * 8 + l8;
        bgp[i]  = Bt + (size_t)(n0 + row) * K + lc * 8;
        boff[i] = (wave * (BN / 4) + i * 8) * 128;
    }

    int a0 = 0,     a1 = 16384,    a2 = 32768;
    int b0 = 49152, b1 = 49152 + BB, b2 = 49152 + 2 * BB;

    #pragma unroll
    for (int i = 0; i < 4; ++i) gload16(agp[i], smem + a0 + aoff[i]);
    #pragma unroll
    for (int i = 0; i < NB; ++i) gload16(bgp[i], smem + b0 + boff[i]);
    if (64 < K) {
        #pragma unroll
        for (int i = 0; i < 4; ++i) gload16(agp[i] + 64, smem + a1 + aoff[i]);
        #pragma unroll
        for (int i = 0; i < NB; ++i) gload16(bgp[i] + 64, smem + b1 + boff[i]);
    }

    for (int k0 = 0; k0 < K; k0 += 64) {
        if (k0 + 64 < K) {
            if constexpr (NB == 2) { WAITV6(); } else { WAITV5(); }
        } else { WAITV0(); }
        __builtin_amdgcn_s_barrier();
        if (k0 + 128 < K) {
            #pragma unroll
            for (int i = 0; i < 4; ++i) gload16(agp[i] + k0 + 128, smem + a2 + aoff[i]);
            #pragma unroll
            for (int i = 0; i < NB; ++i) gload16(bgp[i] + k0 + 128, smem + b2 + boff[i]);
        }
        const unsigned char* abuf = smem + a0;
        const unsigned char* bbuf = smem + b0;
        const int lr = lane & 15;
        const int lk = lane >> 4;
        #pragma unroll
        for (int ks = 0; ks < 2; ++ks) {
            int chunk = ks * 4 + lk;
            short8 af[4], bfr[NF];
            #pragma unroll
            for (int m = 0; m < 4; ++m) {
                int row = wm + m * 16 + lr;
                af[m] = *(const short8*)(abuf + row * 128 + ((chunk * 16) ^ ((row & 7) << 4)));
            }
            #pragma unroll
            for (int n = 0; n < NF; ++n) {
                int nn = wn + n * 16 + lr;
                bfr[n] = *(const short8*)(bbuf + nn * 128 + ((chunk * 16) ^ ((nn & 7) << 4)));
            }
            #pragma unroll
            for (int m = 0; m < 4; ++m)
                #pragma unroll
                for (int n = 0; n < NF; ++n)
                    acc[m][n] = __builtin_amdgcn_mfma_f32_16x16x32_bf16(af[m], bfr[n], acc[m][n], 0, 0, 0);
        }
        int ta = a0; a0 = a1; a1 = a2; a2 = ta;
        int tb = b0; b0 = b1; b1 = b2; b2 = tb;
    }

    const int lr = lane & 15;
    const int lq = lane >> 4;
    float bv[NF];
    #pragma unroll
    for (int n = 0; n < NF; ++n)
        bv[n] = bias ? bias[n0 + wn + n * 16 + lr] : 0.f;
    #pragma unroll
    for (int m = 0; m < 4; ++m) {
        int rbase = m0 + wm + m * 16 + lq * 4;
        #pragma unroll
        for (int j = 0; j < 4; ++j) {
            int row = rbase + j;
            #pragma unroll
            for (int n = 0; n < NF; ++n) {
                int col = n0 + wn + n * 16 + lr;
                float v = acc[m][n][j] + bv[n];
                if (resid) v += resid[(size_t)row * N + col];
                if (GELU_ACT) v = 0.5f * v * (1.f + erff(v * 0.70710678118654752f));
                if (OUT_BF16)
                    ((__hip_bfloat16*)Cout)[(size_t)row * N + col] = __float2bfloat16(v);
                else
                    ((float*)Cout)[(size_t)row * N + col] = v;
            }
        }
    }
}

// ---------------------------------------------------------------------------
// LM-head GEMM (r25/r27, proven best: 155us): dbuf + panel swizzle + NT.
// ---------------------------------------------------------------------------
__global__ __launch_bounds__(256)
void gemm_db_nt(const __hip_bfloat16* __restrict__ A,
                const __hip_bfloat16* __restrict__ Bt,
                float* __restrict__ Cout, int M, int N, int K, int GN)
{
    __shared__ unsigned char smem[65536];
    int mblk, pnl;
    {
        int bid = blockIdx.x;
        int x = bid & 7, j = bid >> 3;
        int pw = GN >> 3;
        int whole = pw * 128;
        if (bid < whole) { pnl = x + 8 * (j >> 4); mblk = j & 15; }
        else { int r = bid - whole; pnl = (pw << 3) + (r >> 4); mblk = r & 15; }
    }
    const int m0 = mblk * 128;
    const int n0 = pnl * 128;
    const int t    = threadIdx.x;
    const int lane = t & 63;
    const int wave = t >> 6;
    const int wm = (wave >> 1) * 64;
    const int wn = (wave & 1) * 64;

    f32x4 acc[4][4];
    #pragma unroll
    for (int i = 0; i < 4; ++i)
        #pragma unroll
        for (int j = 0; j < 4; ++j) {
            acc[i][j][0] = 0.f; acc[i][j][1] = 0.f; acc[i][j][2] = 0.f; acc[i][j][3] = 0.f;
        }

    const int l8 = lane >> 3;
    const int lc = (lane & 7) ^ l8;
    const __hip_bfloat16* agp[4];
    const __hip_bfloat16* bgp[4];
    int aoff[4];
    int boff[4];
    #pragma unroll
    for (int i = 0; i < 4; ++i) {
        int row = wave * 32 + i * 8 + l8;
        agp[i]  = A + (size_t)(m0 + row) * K + lc * 8;
        aoff[i] = (wave * 32 + i * 8) * 128;
        bgp[i]  = Bt + (size_t)(n0 + row) * K + lc * 8;
        boff[i] = (wave * 32 + i * 8) * 128;
    }
    const int aBufOff[2] = { 0, 16384 };
    const int bBufOff[2] = { 32768, 49152 };

    #pragma unroll
    for (int i = 0; i < 4; ++i) gload16(agp[i], smem + aBufOff[0] + aoff[i]);
    #pragma unroll
    for (int i = 0; i < 4; ++i) gload16(bgp[i], smem + bBufOff[0] + boff[i]);
    __syncthreads();

    int cur = 0;
    for (int k0 = 0; k0 < K; k0 += 64) {
        if (k0 + 64 < K) {
            #pragma unroll
            for (int i = 0; i < 4; ++i)
                gload16(agp[i] + k0 + 64, smem + aBufOff[cur ^ 1] + aoff[i]);
            #pragma unroll
            for (int i = 0; i < 4; ++i)
                gload16(bgp[i] + k0 + 64, smem + bBufOff[cur ^ 1] + boff[i]);
        }
        const unsigned char* abuf = smem + aBufOff[cur];
        const unsigned char* bbuf = smem + bBufOff[cur];
        const int lr = lane & 15;
        const int lk = lane >> 4;
        #pragma unroll
        for (int ks = 0; ks < 2; ++ks) {
            int chunk = ks * 4 + lk;
            short8 af[4], bfr[4];
            #pragma unroll
            for (int m = 0; m < 4; ++m) {
                int row = wm + m * 16 + lr;
                af[m] = *(const short8*)(abuf + row * 128 + ((chunk * 16) ^ ((row & 7) << 4)));
            }
            #pragma unroll
            for (int n = 0; n < 4; ++n) {
                int nn = wn + n * 16 + lr;
                bfr[n] = *(const short8*)(bbuf + nn * 128 + ((chunk * 16) ^ ((nn & 7) << 4)));
            }
            #pragma unroll
            for (int m = 0; m < 4; ++m)
                #pragma unroll
                for (int n = 0; n < 4; ++n)
                    acc[m][n] = __builtin_amdgcn_mfma_f32_16x16x32_bf16(af[m], bfr[n], acc[m][n], 0, 0, 0);
        }
        __syncthreads();
        cur ^= 1;
    }

    const int lr = lane & 15;
    const int lq = lane >> 4;
    #pragma unroll
    for (int m = 0; m < 4; ++m) {
        int rbase = m0 + wm + m * 16 + lq * 4;
        #pragma unroll
        for (int j = 0; j < 4; ++j) {
            int row = rbase + j;
            #pragma unroll
            for (int n = 0; n < 4; ++n) {
                int col = n0 + wn + n * 16 + lr;
                __builtin_nontemporal_store(acc[m][n][j],
                    Cout + (size_t)row * N + col);
            }
        }
    }
}

// ---------------------------------------------------------------------------
// MFMA causal attention (r29, proven: T14 async-STAGE + T5 setprio)
// ---------------------------------------------------------------------------
__global__ __launch_bounds__(256)
void attn_mfma(const __hip_bfloat16* __restrict__ qkv,
               __hip_bfloat16* __restrict__ y)
{
    __shared__ short Qs[64][72];
    __shared__ short Ps[64][72];
    __shared__ unsigned char Kl[8192];
    __shared__ short Vt[64][72];

    const int bid = blockIdx.x;
    const int p   = bid >> 5;
    const int qt  = (p < 8) ? (15 - 2 * p) : (2 * (p - 8));
    const int bh  = bid & 31;
    const int b = bh >> 4, h = bh & 15;
    const int t = threadIdx.x, lane = t & 63, w = t >> 6;
    const int lr = lane & 15, lg = lane >> 4;
    const size_t base = (size_t)b * 1024 * 3072;
    const int qbase = qt * 64;

    {
        int row = t >> 2, c = t & 3;
        const short8* qsrc = (const short8*)(qkv + base + (size_t)(qbase + row) * 3072 + h * 64);
        *(short8*)&Qs[row][c * 8]      = qsrc[c];
        *(short8*)&Qs[row][c * 8 + 32] = qsrc[c + 4];
    }
    __syncthreads();

    short8 aq0 = *(const short8*)&Qs[w * 16 + lr][0 * 32 + lg * 8];
    short8 aq1 = *(const short8*)&Qs[w * 16 + lr][1 * 32 + lg * 8];

    f32x4 oacc[4];
    #pragma unroll
    for (int dt = 0; dt < 4; ++dt) { oacc[dt][0]=0.f; oacc[dt][1]=0.f; oacc[dt][2]=0.f; oacc[dt][3]=0.f; }
    float lsum[4] = {0.f, 0.f, 0.f, 0.f};

    const int ntiles = qt + 1;
    const int kkey = t >> 2, kc = t & 3;
    const int vkey = t & 63, vc = t >> 6;

    short8 rk0, rk1, rv0, rv1;
    {
        const short8* ksrc = (const short8*)(qkv + base + (size_t)kkey * 3072 + 1024 + h * 64);
        rk0 = ksrc[kc]; rk1 = ksrc[kc + 4];
        const short8* vsrc = (const short8*)(qkv + base + (size_t)vkey * 3072 + 2048 + h * 64);
        rv0 = vsrc[vc]; rv1 = vsrc[vc + 4];
    }
    {
        int rb = kkey * 128, sw = (kkey & 7) << 4;
        *(short8*)(Kl + rb + ((kc * 16) ^ sw)) = rk0;
        *(short8*)(Kl + rb + (((kc + 4) * 16) ^ sw)) = rk1;
        #pragma unroll
        for (int j = 0; j < 8; ++j) Vt[vc * 8 + j][vkey] = rv0[j];
        #pragma unroll
        for (int j = 0; j < 8; ++j) Vt[(vc + 4) * 8 + j][vkey] = rv1[j];
    }
    __syncthreads();

    for (int tile = 0; tile < ntiles; ++tile) {
        if (tile + 1 < ntiles) {
            const int kb2 = (tile + 1) * 64;
            const short8* ksrc = (const short8*)(qkv + base + (size_t)(kb2 + kkey) * 3072 + 1024 + h * 64);
            rk0 = ksrc[kc]; rk1 = ksrc[kc + 4];
            const short8* vsrc = (const short8*)(qkv + base + (size_t)(kb2 + vkey) * 3072 + 2048 + h * 64);
            rv0 = vsrc[vc]; rv1 = vsrc[vc + 4];
        }

        const int kb = tile * 64;
        f32x4 sacc[4];
        #pragma unroll
        for (int kt = 0; kt < 4; ++kt) { sacc[kt][0]=0.f; sacc[kt][1]=0.f; sacc[kt][2]=0.f; sacc[kt][3]=0.f; }
        __builtin_amdgcn_s_setprio(1);
        #pragma unroll
        for (int ks = 0; ks < 2; ++ks) {
            short8 aq = ks ? aq1 : aq0;
            #pragma unroll
            for (int kt = 0; kt < 4; ++kt) {
                int krow = kt * 16 + lr;
                short8 bk = *(const short8*)(Kl + krow * 128 + (((ks * 4 + lg) * 16) ^ ((krow & 7) << 4)));
                sacc[kt] = __builtin_amdgcn_mfma_f32_16x16x32_bf16(aq, bk, sacc[kt], 0, 0, 0);
            }
        }
        __builtin_amdgcn_s_setprio(0);

        #pragma unroll
        for (int kt = 0; kt < 4; ++kt) {
            int key = kb + kt * 16 + lr;
            #pragma unroll
            for (int j = 0; j < 4; ++j) {
                int q = qbase + w * 16 + lg * 4 + j;
                float pv = (key <= q) ? __expf(sacc[kt][j] * 0.125f) : 0.f;
                lsum[j] += pv;
                Ps[w * 16 + lg * 4 + j][kt * 16 + lr] = (short)f2bf(pv);
            }
        }

        __builtin_amdgcn_s_setprio(1);
        #pragma unroll
        for (int ks = 0; ks < 2; ++ks) {
            short8 ap = *(const short8*)&Ps[w * 16 + lr][ks * 32 + lg * 8];
            #pragma unroll
            for (int dt = 0; dt < 4; ++dt) {
                short8 bv = *(const short8*)&Vt[dt * 16 + lr][ks * 32 + lg * 8];
                oacc[dt] = __builtin_amdgcn_mfma_f32_16x16x32_bf16(ap, bv, oacc[dt], 0, 0, 0);
            }
        }
        __builtin_amdgcn_s_setprio(0);

        if (tile + 1 < ntiles) {
            __syncthreads();
            int rb = kkey * 128, sw = (kkey & 7) << 4;
            *(short8*)(Kl + rb + ((kc * 16) ^ sw)) = rk0;
            *(short8*)(Kl + rb + (((kc + 4) * 16) ^ sw)) = rk1;
            #pragma unroll
            for (int j = 0; j < 8; ++j) Vt[vc * 8 + j][vkey] = rv0[j];
            #pragma unroll
            for (int j = 0; j < 8; ++j) Vt[(vc + 4) * 8 + j][vkey] = rv1[j];
            __syncthreads();
        }
    }

    #pragma unroll
    for (int j = 0; j < 4; ++j) {
        float l = lsum[j];
        l += __shfl_xor(l, 1); l += __shfl_xor(l, 2);
        l += __shfl_xor(l, 4); l += __shfl_xor(l, 8);
        float inv = 1.f / l;
        int qrow = qbase + w * 16 + lg * 4 + j;
        __hip_bfloat16* dst = y + (size_t)(b * 1024 + qrow) * 1024 + h * 64;
        #pragma unroll
        for (int dt = 0; dt < 4; ++dt)
            dst[dt * 16 + lr] = __float2bfloat16(oacc[dt][j] * inv);
    }
}

// ---------------------------------------------------------------------------
// Host launch: r29 config + BN=32 for proj/fc2 (512 blocks = 2/CU).
// ---------------------------------------------------------------------------
extern "C" void kernel_launch(void* const* d_in, const int* in_sizes, int n_in,
                              void* d_out, int out_size, void* d_ws, size_t ws_size,
                              hipStream_t stream)
{
    (void)in_sizes; (void)n_in; (void)out_size; (void)ws_size;

    const int*   ids    = (const int*)d_in[0];
    const float* wte    = (const float*)d_in[1];
    const float* wpe    = (const float*)d_in[2];
    const float* ln1_g  = (const float*)d_in[3];
    const float* ln1_b  = (const float*)d_in[4];
    const float* w_qkv  = (const float*)d_in[5];
    const float* b_qkv  = (const float*)d_in[6];
    const float* w_proj = (const float*)d_in[7];
    const float* b_proj = (const float*)d_in[8];
    const float* ln2_g  = (const float*)d_in[9];
    const float* ln2_b  = (const float*)d_in[10];
    const float* w_fc1  = (const float*)d_in[11];
    const float* b_fc1  = (const float*)d_in[12];
    const float* w_fc2  = (const float*)d_in[13];
    const float* b_fc2  = (const float*)d_in[14];
    const float* lnf_g  = (const float*)d_in[15];
    const float* lnf_b  = (const float*)d_in[16];
    const float* w_lm   = (const float*)d_in[17];

    char* ws = (char*)d_ws;
    __hip_bfloat16* abuf_bf = (__hip_bfloat16*)ws;                    // 4 MB
    float*          hbuf    = (float*)(ws + (4u<<20));                // 8 MB
    __hip_bfloat16* qkvb_bf = (__hip_bfloat16*)(ws + (12u<<20));      // 12 MB
    __hip_bfloat16* ybuf_bf = (__hip_bfloat16*)(ws + (24u<<20));      // 4 MB
    __hip_bfloat16* mbuf_bf = (__hip_bfloat16*)(ws + (28u<<20));      // 16 MB
    __hip_bfloat16* wlm_bf  = (__hip_bfloat16*)(ws + (4u<<20));       // 65.5 MB (end)

    __hip_bfloat16* wq_bf = (__hip_bfloat16*)d_out;
    __hip_bfloat16* wp_bf = wq_bf + (size_t)4*1024*3072;
    __hip_bfloat16* w1_bf = wp_bf + (size_t)4*1024*1024;
    __hip_bfloat16* w2_bf = w1_bf + (size_t)4*1024*4096;

    float* out = (float*)d_out;   // f32 logits

    tc_kernel<<<dim3(16, 48, 4), 256, 0, stream>>>(w_qkv,  wq_bf, 3072, 1024);
    tc_kernel<<<dim3(16, 16, 4), 256, 0, stream>>>(w_proj, wp_bf, 1024, 1024);
    tc_kernel<<<dim3(16, 64, 4), 256, 0, stream>>>(w_fc1,  w1_bf, 4096, 1024);
    tc_kernel<<<dim3(64, 16, 4), 256, 0, stream>>>(w_fc2,  w2_bf, 1024, 4096);

    embed_kernel<<<2048, 256, 0, stream>>>(ids, wte, wpe, hbuf);

    for (int l = 0; l < 4; ++l) {
        ln_kernel<<<2048, 256, 0, stream>>>(hbuf, ln1_g + l*1024, ln1_b + l*1024, abuf_bf);
        gemm_p3<true,false,64><<<16*48, 256, 0, stream>>>(
            abuf_bf, wq_bf + (size_t)l*1024*3072, b_qkv + l*3072, nullptr, qkvb_bf, 2048, 3072, 1024, 48);
        attn_mfma<<<512, 256, 0, stream>>>(qkvb_bf, ybuf_bf);
        gemm_p3<false,false,32><<<16*32, 256, 0, stream>>>(
            ybuf_bf, wp_bf + (size_t)l*1024*1024, b_proj + l*1024, hbuf, hbuf, 2048, 1024, 1024, 32);
        ln_kernel<<<2048, 256, 0, stream>>>(hbuf, ln2_g + l*1024, ln2_b + l*1024, abuf_bf);
        gemm_p3<true,true,64><<<16*64, 256, 0, stream>>>(
            abuf_bf, w1_bf + (size_t)l*1024*4096, b_fc1 + l*4096, nullptr, mbuf_bf, 2048, 4096, 1024, 64);
        gemm_p3<false,false,32><<<16*32, 256, 0, stream>>>(
            mbuf_bf, w2_bf + (size_t)l*4096*1024, b_fc2 + l*1024, hbuf, hbuf, 2048, 1024, 4096, 32);
    }

    ln_kernel<<<2048, 256, 0, stream>>>(hbuf, lnf_g, lnf_b, abuf_bf);
    tc_kernel<<<dim3(16, 500, 1), 256, 0, stream>>>(w_lm, wlm_bf, 32000, 1024);
    gemm_db_nt<<<16*250, 256, 0, stream>>>(
        abuf_bf, wlm_bf, out, 2048, 32000, 1024, 250);
}